// Round 1
// baseline (2970.145 us; speedup 1.0000x reference)
//
#include <hip/hip_runtime.h>

#define NFEAT 128

// ---------------- degree histograms ----------------
__global__ void deg_kernel(const int* __restrict__ src, const int* __restrict__ dst,
                           int E, int* __restrict__ out_deg, int* __restrict__ in_deg) {
    int i = blockIdx.x * blockDim.x + threadIdx.x;
    if (i < E) {
        atomicAdd(&out_deg[src[i]], 1);
        atomicAdd(&in_deg[dst[i]], 1);
    }
}

// ---------------- norms: rsqrt(max(deg,1)) ----------------
__global__ void norm_kernel(const int* __restrict__ od, const int* __restrict__ id,
                            float* __restrict__ onorm, float* __restrict__ inorm, int N) {
    int i = blockIdx.x * blockDim.x + threadIdx.x;
    if (i < N) {
        onorm[i] = rsqrtf((float)max(od[i], 1));
        inorm[i] = rsqrtf((float)max(id[i], 1));
    }
}

// ---------------- scatter: agg[dst] += x[src] * onorm[src] ----------------
// 32 threads per edge, 4 features (float4) per thread.
__global__ __launch_bounds__(256)
void scatter_kernel(const float* __restrict__ x, const int* __restrict__ src,
                    const int* __restrict__ dst, const float* __restrict__ onorm,
                    float* __restrict__ agg, int E) {
    int tid = blockIdx.x * blockDim.x + threadIdx.x;
    int e = tid >> 5;
    if (e >= E) return;
    int f = (tid & 31) * 4;
    int s = src[e];
    int d = dst[e];
    float nrm = onorm[s];
    const float4 xv = *reinterpret_cast<const float4*>(&x[s * NFEAT + f]);
    float* ap = &agg[d * NFEAT + f];
    atomicAdd(ap + 0, xv.x * nrm);
    atomicAdd(ap + 1, xv.y * nrm);
    atomicAdd(ap + 2, xv.z * nrm);
    atomicAdd(ap + 3, xv.w * nrm);
}

// ---------------- per-row projection: out = (agg * inorm) @ W + b (in-place) ----------------
// W (128x128 f32, 64KB) staged in LDS. One wave per row; lane computes cols {2*lane, 2*lane+1}.
__global__ __launch_bounds__(256)
void mm_kernel(float* __restrict__ out, const float* __restrict__ inorm,
               const float* __restrict__ W, const float* __restrict__ b, int N) {
    __shared__ float Wl[NFEAT * NFEAT];      // 64 KiB
    __shared__ float rowl[4][NFEAT];

    // cooperative W load: 4096 float4
    for (int i = threadIdx.x; i < (NFEAT * NFEAT) / 4; i += 256) {
        reinterpret_cast<float4*>(Wl)[i] = reinterpret_cast<const float4*>(W)[i];
    }
    __syncthreads();

    const int wave = threadIdx.x >> 6;
    const int lane = threadIdx.x & 63;
    const int c0 = 2 * lane;
    const float b0 = b[c0];
    const float b1 = b[c0 + 1];
    const int rows_per_iter = gridDim.x * 4;

    for (int row0 = blockIdx.x * 4; row0 < N; row0 += rows_per_iter) {
        int row = row0 + wave;
        bool valid = (row < N);
        float2 v = make_float2(0.f, 0.f);
        float s = 0.f;
        if (valid) {
            v = *reinterpret_cast<const float2*>(&out[row * NFEAT + c0]);
            s = inorm[row];
        }
        rowl[wave][c0]     = v.x * s;
        rowl[wave][c0 + 1] = v.y * s;
        __syncthreads();

        float acc0 = b0, acc1 = b1;
        #pragma unroll
        for (int k = 0; k < NFEAT; ++k) {
            float a = rowl[wave][k];
            acc0 = fmaf(a, Wl[k * NFEAT + c0],     acc0);
            acc1 = fmaf(a, Wl[k * NFEAT + c0 + 1], acc1);
        }
        if (valid) {
            *reinterpret_cast<float2*>(&out[row * NFEAT + c0]) = make_float2(acc0, acc1);
        }
        __syncthreads();
    }
}

extern "C" void kernel_launch(void* const* d_in, const int* in_sizes, int n_in,
                              void* d_out, int out_size, void* d_ws, size_t ws_size,
                              hipStream_t stream) {
    const float* x   = (const float*)d_in[0];
    const int*   src = (const int*)d_in[1];
    const int*   dst = (const int*)d_in[2];
    const float* W   = (const float*)d_in[3];
    const float* b   = (const float*)d_in[4];

    const int N = in_sizes[0] / NFEAT;   // 100000
    const int E = in_sizes[1];           // 1600000
    float* out = (float*)d_out;

    // workspace layout: out_deg[N] int | in_deg[N] int | onorm[N] f32 | inorm[N] f32
    int*   out_deg = (int*)d_ws;
    int*   in_deg  = out_deg + N;
    float* onorm   = (float*)(in_deg + N);
    float* inorm   = onorm + N;

    hipMemsetAsync(d_ws, 0, (size_t)2 * N * sizeof(int), stream);
    hipMemsetAsync(d_out, 0, (size_t)out_size * sizeof(float), stream);

    deg_kernel<<<(E + 255) / 256, 256, 0, stream>>>(src, dst, E, out_deg, in_deg);
    norm_kernel<<<(N + 255) / 256, 256, 0, stream>>>(out_deg, in_deg, onorm, inorm, N);

    // 32 threads/edge
    long long scatter_threads = (long long)E * 32;
    int scatter_blocks = (int)((scatter_threads + 255) / 256);
    scatter_kernel<<<scatter_blocks, 256, 0, stream>>>(x, src, dst, onorm, out, E);

    mm_kernel<<<1024, 256, 0, stream>>>(out, inorm, W, b, N);
}

// Round 2
// 527.574 us; speedup vs baseline: 5.6298x; 5.6298x over previous
//
#include <hip/hip_runtime.h>

#define NFEAT 128
#define SCAN_BLK 512

// ---------------- degree histograms ----------------
__global__ void deg_kernel(const int* __restrict__ src, const int* __restrict__ dst,
                           int E, int* __restrict__ out_deg, int* __restrict__ in_deg) {
    int i = blockIdx.x * blockDim.x + threadIdx.x;
    if (i < E) {
        atomicAdd(&out_deg[src[i]], 1);
        atomicAdd(&in_deg[dst[i]], 1);
    }
}

// ---------------- norms: rsqrt(max(deg,1)) ----------------
__global__ void norm_kernel(const int* __restrict__ od, const int* __restrict__ id,
                            float* __restrict__ onorm, float* __restrict__ inorm, int N) {
    int i = blockIdx.x * blockDim.x + threadIdx.x;
    if (i < N) {
        onorm[i] = rsqrtf((float)max(od[i], 1));
        inorm[i] = rsqrtf((float)max(id[i], 1));
    }
}

// ---------------- scan stage 1: per-block exclusive scan of in_deg ----------------
__global__ void scan1_kernel(const int* __restrict__ deg, int N,
                             int* __restrict__ row_start, int* __restrict__ bsums) {
    __shared__ int tmp[SCAN_BLK];
    int i = blockIdx.x * SCAN_BLK + threadIdx.x;
    int v = (i < N) ? deg[i] : 0;
    tmp[threadIdx.x] = v;
    __syncthreads();
    for (int off = 1; off < SCAN_BLK; off <<= 1) {
        int t = (threadIdx.x >= off) ? tmp[threadIdx.x - off] : 0;
        __syncthreads();
        tmp[threadIdx.x] += t;
        __syncthreads();
    }
    if (i < N) row_start[i] = tmp[threadIdx.x] - v;   // exclusive
    if (threadIdx.x == SCAN_BLK - 1) bsums[blockIdx.x] = tmp[threadIdx.x];
}

// ---------------- scan stage 2: exclusive scan of block sums (single block) ----------------
__global__ void scan2_kernel(int* __restrict__ bsums, int nblk) {
    __shared__ int tmp[1024];
    int t = threadIdx.x;
    int v = (t < nblk) ? bsums[t] : 0;
    tmp[t] = v;
    __syncthreads();
    for (int off = 1; off < 1024; off <<= 1) {
        int u = (t >= off) ? tmp[t - off] : 0;
        __syncthreads();
        tmp[t] += u;
        __syncthreads();
    }
    if (t < nblk) bsums[t] = tmp[t] - v;              // exclusive block offsets
}

// ---------------- scan stage 3: add block offsets; set row_start[N]=E ----------------
__global__ void scan3_kernel(int* __restrict__ row_start, const int* __restrict__ bsums,
                             int N, int E) {
    int i = blockIdx.x * SCAN_BLK + threadIdx.x;
    if (i < N) row_start[i] += bsums[blockIdx.x];
    if (i == 0) row_start[N] = E;
}

// ---------------- CSR fill: csr_src[row_start[d] + slot] = src ----------------
__global__ void fill_kernel(const int* __restrict__ src, const int* __restrict__ dst, int E,
                            const int* __restrict__ row_start, int* __restrict__ cursor,
                            int* __restrict__ csr_src) {
    int i = blockIdx.x * blockDim.x + threadIdx.x;
    if (i < E) {
        int d = dst[i];
        int slot = atomicAdd(&cursor[d], 1);
        csr_src[row_start[d] + slot] = src[i];
    }
}

// ---------------- gather-aggregate: out[n] = inorm[n] * sum_e onorm[src_e] * x[src_e] ----------------
// One wave per node; lane handles 2 features (float2). 4 waves/block.
__global__ __launch_bounds__(256)
void agg_kernel(const float* __restrict__ x, const int* __restrict__ csr_src,
                const int* __restrict__ row_start, const float* __restrict__ onorm,
                const float* __restrict__ inorm, float* __restrict__ out, int N) {
    int node = blockIdx.x * 4 + (threadIdx.x >> 6);
    if (node >= N) return;
    int lane = threadIdx.x & 63;
    int beg = row_start[node];
    int end = row_start[node + 1];

    float2 acc0 = make_float2(0.f, 0.f);
    float2 acc1 = make_float2(0.f, 0.f);
    int i = beg;
    for (; i + 1 < end; i += 2) {
        int s0 = csr_src[i];
        int s1 = csr_src[i + 1];
        float c0 = onorm[s0];
        float c1 = onorm[s1];
        float2 xv0 = *reinterpret_cast<const float2*>(&x[s0 * NFEAT + 2 * lane]);
        float2 xv1 = *reinterpret_cast<const float2*>(&x[s1 * NFEAT + 2 * lane]);
        acc0.x = fmaf(xv0.x, c0, acc0.x);
        acc0.y = fmaf(xv0.y, c0, acc0.y);
        acc1.x = fmaf(xv1.x, c1, acc1.x);
        acc1.y = fmaf(xv1.y, c1, acc1.y);
    }
    if (i < end) {
        int s0 = csr_src[i];
        float c0 = onorm[s0];
        float2 xv0 = *reinterpret_cast<const float2*>(&x[s0 * NFEAT + 2 * lane]);
        acc0.x = fmaf(xv0.x, c0, acc0.x);
        acc0.y = fmaf(xv0.y, c0, acc0.y);
    }
    float in_n = inorm[node];
    float2 r = make_float2((acc0.x + acc1.x) * in_n, (acc0.y + acc1.y) * in_n);
    *reinterpret_cast<float2*>(&out[node * NFEAT + 2 * lane]) = r;
}

// ---------------- per-row projection: out = agg @ W + b (in-place) ----------------
__global__ __launch_bounds__(256)
void mm_kernel(float* __restrict__ out, const float* __restrict__ W,
               const float* __restrict__ b, int N) {
    __shared__ float Wl[NFEAT * NFEAT];      // 64 KiB
    __shared__ float rowl[4][NFEAT];

    for (int i = threadIdx.x; i < (NFEAT * NFEAT) / 4; i += 256) {
        reinterpret_cast<float4*>(Wl)[i] = reinterpret_cast<const float4*>(W)[i];
    }
    __syncthreads();

    const int wave = threadIdx.x >> 6;
    const int lane = threadIdx.x & 63;
    const int c0 = 2 * lane;
    const float b0 = b[c0];
    const float b1 = b[c0 + 1];
    const int rows_per_iter = gridDim.x * 4;

    for (int row0 = blockIdx.x * 4; row0 < N; row0 += rows_per_iter) {
        int row = row0 + wave;
        bool valid = (row < N);
        float2 v = make_float2(0.f, 0.f);
        if (valid) {
            v = *reinterpret_cast<const float2*>(&out[row * NFEAT + c0]);
        }
        rowl[wave][c0]     = v.x;
        rowl[wave][c0 + 1] = v.y;
        __syncthreads();

        float acc0 = b0, acc1 = b1;
        #pragma unroll
        for (int k = 0; k < NFEAT; ++k) {
            float a = rowl[wave][k];
            acc0 = fmaf(a, Wl[k * NFEAT + c0],     acc0);
            acc1 = fmaf(a, Wl[k * NFEAT + c0 + 1], acc1);
        }
        if (valid) {
            *reinterpret_cast<float2*>(&out[row * NFEAT + c0]) = make_float2(acc0, acc1);
        }
        __syncthreads();
    }
}

extern "C" void kernel_launch(void* const* d_in, const int* in_sizes, int n_in,
                              void* d_out, int out_size, void* d_ws, size_t ws_size,
                              hipStream_t stream) {
    const float* x   = (const float*)d_in[0];
    const int*   src = (const int*)d_in[1];
    const int*   dst = (const int*)d_in[2];
    const float* W   = (const float*)d_in[3];
    const float* b   = (const float*)d_in[4];

    const int N = in_sizes[0] / NFEAT;   // 100000
    const int E = in_sizes[1];           // 1600000
    float* out = (float*)d_out;

    // workspace layout (ints unless noted):
    // [out_deg N][in_deg N][cursor N]  <- zeroed together
    // [onorm N f32][inorm N f32][row_start N+1][bsums 1024][csr_src E]
    int*   out_deg   = (int*)d_ws;
    int*   in_deg    = out_deg + N;
    int*   cursor    = in_deg + N;
    float* onorm     = (float*)(cursor + N);
    float* inorm     = onorm + N;
    int*   row_start = (int*)(inorm + N);
    int*   bsums     = row_start + (N + 1);
    int*   csr_src   = bsums + 1024;

    hipMemsetAsync(d_ws, 0, (size_t)3 * N * sizeof(int), stream);

    deg_kernel<<<(E + 255) / 256, 256, 0, stream>>>(src, dst, E, out_deg, in_deg);
    norm_kernel<<<(N + 255) / 256, 256, 0, stream>>>(out_deg, in_deg, onorm, inorm, N);

    int nblk = (N + SCAN_BLK - 1) / SCAN_BLK;          // 196 for N=100000
    scan1_kernel<<<nblk, SCAN_BLK, 0, stream>>>(in_deg, N, row_start, bsums);
    scan2_kernel<<<1, 1024, 0, stream>>>(bsums, nblk);
    scan3_kernel<<<nblk, SCAN_BLK, 0, stream>>>(row_start, bsums, N, E);

    fill_kernel<<<(E + 255) / 256, 256, 0, stream>>>(src, dst, E, row_start, cursor, csr_src);

    agg_kernel<<<(N + 3) / 4, 256, 0, stream>>>(x, csr_src, row_start, onorm, inorm, out, N);

    mm_kernel<<<1024, 256, 0, stream>>>(out, W, b, N);
}

// Round 3
// 482.870 us; speedup vs baseline: 6.1510x; 1.0926x over previous
//
#include <hip/hip_runtime.h>

#define NFEAT 128
#define SCAN_BLK 512

// ---------------- degree histograms ----------------
__global__ void deg_kernel(const int* __restrict__ src, const int* __restrict__ dst,
                           int E, int* __restrict__ out_deg, int* __restrict__ in_deg) {
    int i = blockIdx.x * blockDim.x + threadIdx.x;
    if (i < E) {
        atomicAdd(&out_deg[src[i]], 1);
        atomicAdd(&in_deg[dst[i]], 1);
    }
}

// ---------------- scan stage 1: per-block exclusive scan of in_deg ----------------
__global__ void scan1_kernel(const int* __restrict__ deg, int N,
                             int* __restrict__ row_start, int* __restrict__ bsums) {
    __shared__ int tmp[SCAN_BLK];
    int i = blockIdx.x * SCAN_BLK + threadIdx.x;
    int v = (i < N) ? deg[i] : 0;
    tmp[threadIdx.x] = v;
    __syncthreads();
    for (int off = 1; off < SCAN_BLK; off <<= 1) {
        int t = (threadIdx.x >= off) ? tmp[threadIdx.x - off] : 0;
        __syncthreads();
        tmp[threadIdx.x] += t;
        __syncthreads();
    }
    if (i < N) row_start[i] = tmp[threadIdx.x] - v;   // exclusive
    if (threadIdx.x == SCAN_BLK - 1) bsums[blockIdx.x] = tmp[threadIdx.x];
}

// ---------------- scan stage 2: exclusive scan of block sums (single block) ----------------
__global__ void scan2_kernel(int* __restrict__ bsums, int nblk) {
    __shared__ int tmp[1024];
    int t = threadIdx.x;
    int v = (t < nblk) ? bsums[t] : 0;
    tmp[t] = v;
    __syncthreads();
    for (int off = 1; off < 1024; off <<= 1) {
        int u = (t >= off) ? tmp[t - off] : 0;
        __syncthreads();
        tmp[t] += u;
        __syncthreads();
    }
    if (t < nblk) bsums[t] = tmp[t] - v;              // exclusive block offsets
}

// ---------------- scan3 + norms + cursor init (fused) ----------------
__global__ void scan3_norm_kernel(int* __restrict__ row_start, const int* __restrict__ bsums,
                                  const int* __restrict__ od, const int* __restrict__ id,
                                  float* __restrict__ onorm, float* __restrict__ inorm,
                                  int* __restrict__ cursor, int N, int E) {
    int i = blockIdx.x * SCAN_BLK + threadIdx.x;
    if (i < N) {
        int rs = row_start[i] + bsums[blockIdx.x];
        row_start[i] = rs;
        cursor[i] = rs;                                // fill uses cursor directly
        onorm[i] = rsqrtf((float)max(od[i], 1));
        inorm[i] = rsqrtf((float)max(id[i], 1));
    }
    if (i == 0) row_start[N] = E;
}

// ---------------- CSR fill: csr_src[atomicAdd(cursor[d])] = src ----------------
__global__ void fill_kernel(const int* __restrict__ src, const int* __restrict__ dst, int E,
                            int* __restrict__ cursor, int* __restrict__ csr_src) {
    int i = blockIdx.x * blockDim.x + threadIdx.x;
    if (i < E) {
        int d = dst[i];
        int slot = atomicAdd(&cursor[d], 1);
        csr_src[slot] = src[i];
    }
}

// ---------------- gather-aggregate: out[n] = inorm[n] * sum_e onorm[src_e] * x[src_e] ----------------
// Half-wave (32 lanes) per node; lane handles 4 features (float4). 8 nodes/block.
__global__ __launch_bounds__(256)
void agg_kernel(const float* __restrict__ x, const int* __restrict__ csr_src,
                const int* __restrict__ row_start, const float* __restrict__ onorm,
                const float* __restrict__ inorm, float* __restrict__ out, int N) {
    int node = blockIdx.x * 8 + (threadIdx.x >> 5);
    if (node >= N) return;
    int lf = threadIdx.x & 31;
    int beg = row_start[node];
    int end = row_start[node + 1];

    float4 acc0 = make_float4(0.f, 0.f, 0.f, 0.f);
    float4 acc1 = make_float4(0.f, 0.f, 0.f, 0.f);
    int i = beg;
    for (; i + 1 < end; i += 2) {
        int s0 = csr_src[i];
        int s1 = csr_src[i + 1];
        float c0 = onorm[s0];
        float c1 = onorm[s1];
        float4 xv0 = *reinterpret_cast<const float4*>(&x[(size_t)s0 * NFEAT + lf * 4]);
        float4 xv1 = *reinterpret_cast<const float4*>(&x[(size_t)s1 * NFEAT + lf * 4]);
        acc0.x = fmaf(xv0.x, c0, acc0.x); acc0.y = fmaf(xv0.y, c0, acc0.y);
        acc0.z = fmaf(xv0.z, c0, acc0.z); acc0.w = fmaf(xv0.w, c0, acc0.w);
        acc1.x = fmaf(xv1.x, c1, acc1.x); acc1.y = fmaf(xv1.y, c1, acc1.y);
        acc1.z = fmaf(xv1.z, c1, acc1.z); acc1.w = fmaf(xv1.w, c1, acc1.w);
    }
    if (i < end) {
        int s0 = csr_src[i];
        float c0 = onorm[s0];
        float4 xv0 = *reinterpret_cast<const float4*>(&x[(size_t)s0 * NFEAT + lf * 4]);
        acc0.x = fmaf(xv0.x, c0, acc0.x); acc0.y = fmaf(xv0.y, c0, acc0.y);
        acc0.z = fmaf(xv0.z, c0, acc0.z); acc0.w = fmaf(xv0.w, c0, acc0.w);
    }
    float in_n = inorm[node];
    float4 r;
    r.x = (acc0.x + acc1.x) * in_n;
    r.y = (acc0.y + acc1.y) * in_n;
    r.z = (acc0.z + acc1.z) * in_n;
    r.w = (acc0.w + acc1.w) * in_n;
    *reinterpret_cast<float4*>(&out[(size_t)node * NFEAT + lf * 4]) = r;
}

// ---------------- projection: out = agg @ W + b (in-place) ----------------
// 512 threads = 8 waves; each wave owns 8 rows. Lane owns 2 cols. W f32 in LDS.
// Row values are wave-uniform-address loads (scalarizable). agg/outp alias (in-place):
// intentionally NOT __restrict__ so program order (all loads before stores) is preserved.
__global__ __launch_bounds__(512)
void mm_kernel(const float* agg, float* outp, const float* __restrict__ W,
               const float* __restrict__ b, int N) {
    __shared__ float Wl[NFEAT * NFEAT];      // 64 KiB

    for (int i = threadIdx.x; i < (NFEAT * NFEAT) / 4; i += 512) {
        reinterpret_cast<float4*>(Wl)[i] = reinterpret_cast<const float4*>(W)[i];
    }
    __syncthreads();

    const int wave = threadIdx.x >> 6;
    const int lane = threadIdx.x & 63;
    const int c0 = 2 * lane;
    const int r0 = (blockIdx.x * 8 + wave) * 8;      // 8 rows per wave
    if (r0 >= N) return;

    const float b0 = b[c0];
    const float b1 = b[c0 + 1];

    float acc[8][2];
    #pragma unroll
    for (int r = 0; r < 8; ++r) { acc[r][0] = b0; acc[r][1] = b1; }

    const float* arow = agg + (size_t)r0 * NFEAT;

    for (int k4 = 0; k4 < NFEAT; k4 += 4) {
        float4 a[8];
        #pragma unroll
        for (int r = 0; r < 8; ++r) {
            a[r] = *reinterpret_cast<const float4*>(arow + r * NFEAT + k4);
        }
        #pragma unroll
        for (int kk = 0; kk < 4; ++kk) {
            float2 w = *reinterpret_cast<const float2*>(&Wl[(k4 + kk) * NFEAT + c0]);
            #pragma unroll
            for (int r = 0; r < 8; ++r) {
                float av = (kk == 0) ? a[r].x : (kk == 1) ? a[r].y : (kk == 2) ? a[r].z : a[r].w;
                acc[r][0] = fmaf(av, w.x, acc[r][0]);
                acc[r][1] = fmaf(av, w.y, acc[r][1]);
            }
        }
    }

    #pragma unroll
    for (int r = 0; r < 8; ++r) {
        *reinterpret_cast<float2*>(&outp[(size_t)(r0 + r) * NFEAT + c0]) =
            make_float2(acc[r][0], acc[r][1]);
    }
}

extern "C" void kernel_launch(void* const* d_in, const int* in_sizes, int n_in,
                              void* d_out, int out_size, void* d_ws, size_t ws_size,
                              hipStream_t stream) {
    const float* x   = (const float*)d_in[0];
    const int*   src = (const int*)d_in[1];
    const int*   dst = (const int*)d_in[2];
    const float* W   = (const float*)d_in[3];
    const float* b   = (const float*)d_in[4];

    const int N = in_sizes[0] / NFEAT;   // 100000
    const int E = in_sizes[1];           // 1600000
    float* out = (float*)d_out;

    // ws layout (ints unless noted):
    // [out_deg N][in_deg N]  <- zeroed
    // [cursor N][onorm N f32][inorm N f32][row_start N+1][bsums 1024][csr_src E]
    int*   out_deg   = (int*)d_ws;
    int*   in_deg    = out_deg + N;
    int*   cursor    = in_deg + N;
    float* onorm     = (float*)(cursor + N);
    float* inorm     = onorm + N;
    int*   row_start = (int*)(inorm + N);
    int*   bsums     = row_start + (N + 1);
    int*   csr_src   = bsums + 1024;

    hipMemsetAsync(d_ws, 0, (size_t)2 * N * sizeof(int), stream);

    deg_kernel<<<(E + 255) / 256, 256, 0, stream>>>(src, dst, E, out_deg, in_deg);

    int nblk = (N + SCAN_BLK - 1) / SCAN_BLK;          // 196
    scan1_kernel<<<nblk, SCAN_BLK, 0, stream>>>(in_deg, N, row_start, bsums);
    scan2_kernel<<<1, 1024, 0, stream>>>(bsums, nblk);
    scan3_norm_kernel<<<nblk, SCAN_BLK, 0, stream>>>(row_start, bsums, out_deg, in_deg,
                                                     onorm, inorm, cursor, N, E);

    fill_kernel<<<(E + 255) / 256, 256, 0, stream>>>(src, dst, E, cursor, csr_src);

    agg_kernel<<<(N + 7) / 8, 256, 0, stream>>>(x, csr_src, row_start, onorm, inorm, out, N);

    // 8 waves * 8 rows = 64 rows per block
    mm_kernel<<<(N + 63) / 64, 512, 0, stream>>>(out, out, W, b, N);
}

// Round 4
// 358.182 us; speedup vs baseline: 8.2923x; 1.3481x over previous
//
#include <hip/hip_runtime.h>

#define NFEAT 128
#define BSHIFT 9
#define BNODES 512            // 1 << BSHIFT
#define NBMAX 256             // max buckets (N <= 131072)
#define CHUNK 4096            // edges per partition block

// ---------------- out-degree histogram (src) ----------------
__global__ void deg_kernel(const int* __restrict__ src, int E, int* __restrict__ out_deg) {
    int i = blockIdx.x * blockDim.x + threadIdx.x;
    if (i < E) atomicAdd(&out_deg[src[i]], 1);
}

// ---------------- pass A0: per-bucket edge counts ----------------
__global__ __launch_bounds__(256)
void bucket_count_kernel(const int* __restrict__ dst, int E,
                         int* __restrict__ bucket_cnt, int NB) {
    __shared__ int cnt[NBMAX];
    for (int i = threadIdx.x; i < NB; i += 256) cnt[i] = 0;
    __syncthreads();
    int base = blockIdx.x * CHUNK;
    int end = min(base + CHUNK, E);
    for (int j = base + threadIdx.x; j < end; j += 256)
        atomicAdd(&cnt[dst[j] >> BSHIFT], 1);
    __syncthreads();
    for (int i = threadIdx.x; i < NB; i += 256)
        if (cnt[i]) atomicAdd(&bucket_cnt[i], cnt[i]);
}

// ---------------- pass A1: scan bucket counts -> base & cursor ----------------
__global__ void bucket_scan_kernel(const int* __restrict__ bucket_cnt,
                                   int* __restrict__ bucket_base,
                                   int* __restrict__ bucket_cursor, int NB) {
    __shared__ int sa[256], sb[256];
    int tid = threadIdx.x;
    int v = (tid < NB) ? bucket_cnt[tid] : 0;
    sa[tid] = v;
    __syncthreads();
    int* s = sa; int* t = sb;
    for (int d = 1; d < 256; d <<= 1) {
        t[tid] = s[tid] + (tid >= d ? s[tid - d] : 0);
        __syncthreads();
        int* tmp = s; s = t; t = tmp;
    }
    int incl = s[tid];
    int excl = incl - v;
    if (tid < NB) { bucket_base[tid] = excl; bucket_cursor[tid] = excl; }
    if (tid == 255) bucket_base[NB] = incl;   // = E
}

// ---------------- pass A2: partition edges into bucket-ordered packed array ----------------
// packed = ((dst & 511) << 17) | src   (src < 2^17)
__global__ __launch_bounds__(256)
void partition_kernel(const int* __restrict__ src, const int* __restrict__ dst, int E,
                      int* __restrict__ bucket_cursor, int* __restrict__ packed, int NB) {
    __shared__ int cnt[NBMAX];
    for (int i = threadIdx.x; i < NB; i += 256) cnt[i] = 0;
    __syncthreads();
    int base = blockIdx.x * CHUNK;
    int end = min(base + CHUNK, E);
    for (int j = base + threadIdx.x; j < end; j += 256)
        atomicAdd(&cnt[dst[j] >> BSHIFT], 1);
    __syncthreads();
    for (int i = threadIdx.x; i < NB; i += 256) {
        int c = cnt[i];
        cnt[i] = c ? atomicAdd(&bucket_cursor[i], c) : 0;   // cnt becomes global run base
    }
    __syncthreads();
    for (int j = base + threadIdx.x; j < end; j += 256) {
        int d = dst[j];
        int b = d >> BSHIFT;
        int pos = atomicAdd(&cnt[b], 1);
        packed[pos] = ((d & (BNODES - 1)) << 17) | src[j];
    }
}

// ---------------- pass B: per-bucket CSR fill (one block per bucket) ----------------
// All scattered writes land in this bucket's ~32KB csr window -> single-XCD L2 resident.
__global__ __launch_bounds__(512)
void binfill_kernel(const int* __restrict__ packed, const int* __restrict__ bucket_base,
                    int* __restrict__ row_start, float* __restrict__ inorm,
                    int* __restrict__ csr_src, int N, int E) {
    __shared__ int cnt[BNODES];
    __shared__ int sa[BNODES], sb[BNODES];
    int bkt = blockIdx.x;
    int node0 = bkt << BSHIFT;
    int nn = min(BNODES, N - node0);
    int beg = bucket_base[bkt];
    int end = bucket_base[bkt + 1];
    int tid = threadIdx.x;

    cnt[tid] = 0;
    __syncthreads();
    for (int i = beg + tid; i < end; i += 512)
        atomicAdd(&cnt[packed[i] >> 17], 1);
    __syncthreads();

    int v = cnt[tid];
    sa[tid] = v;
    __syncthreads();
    int* s = sa; int* t = sb;
    for (int d = 1; d < 512; d <<= 1) {
        t[tid] = s[tid] + (tid >= d ? s[tid - d] : 0);
        __syncthreads();
        int* tmp = s; s = t; t = tmp;
    }
    int excl = s[tid] - v;

    if (tid < nn) {
        row_start[node0 + tid] = beg + excl;
        inorm[node0 + tid] = rsqrtf((float)max(v, 1));
    }
    if (bkt == 0 && tid == 0) row_start[N] = E;
    __syncthreads();

    cnt[tid] = beg + excl;          // reuse as global cursor
    __syncthreads();
    for (int i = beg + tid; i < end; i += 512) {
        int p = packed[i];
        int slot = atomicAdd(&cnt[p >> 17], 1);
        csr_src[slot] = p & 0x1FFFF;
    }
}

// ---------------- gather-aggregate ----------------
// Half-wave (32 lanes) per node; lane handles 4 features (float4). onorm fused (rsqrt of out_deg).
__global__ __launch_bounds__(256)
void agg_kernel(const float* __restrict__ x, const int* __restrict__ csr_src,
                const int* __restrict__ row_start, const int* __restrict__ out_deg,
                const float* __restrict__ inorm, float* __restrict__ out, int N) {
    int node = blockIdx.x * 8 + (threadIdx.x >> 5);
    if (node >= N) return;
    int lf = threadIdx.x & 31;
    int beg = row_start[node];
    int end = row_start[node + 1];

    float4 acc0 = make_float4(0.f, 0.f, 0.f, 0.f);
    float4 acc1 = make_float4(0.f, 0.f, 0.f, 0.f);
    int i = beg;
    for (; i + 1 < end; i += 2) {
        int s0 = csr_src[i];
        int s1 = csr_src[i + 1];
        float c0 = rsqrtf((float)max(out_deg[s0], 1));
        float c1 = rsqrtf((float)max(out_deg[s1], 1));
        float4 xv0 = *reinterpret_cast<const float4*>(&x[(size_t)s0 * NFEAT + lf * 4]);
        float4 xv1 = *reinterpret_cast<const float4*>(&x[(size_t)s1 * NFEAT + lf * 4]);
        acc0.x = fmaf(xv0.x, c0, acc0.x); acc0.y = fmaf(xv0.y, c0, acc0.y);
        acc0.z = fmaf(xv0.z, c0, acc0.z); acc0.w = fmaf(xv0.w, c0, acc0.w);
        acc1.x = fmaf(xv1.x, c1, acc1.x); acc1.y = fmaf(xv1.y, c1, acc1.y);
        acc1.z = fmaf(xv1.z, c1, acc1.z); acc1.w = fmaf(xv1.w, c1, acc1.w);
    }
    if (i < end) {
        int s0 = csr_src[i];
        float c0 = rsqrtf((float)max(out_deg[s0], 1));
        float4 xv0 = *reinterpret_cast<const float4*>(&x[(size_t)s0 * NFEAT + lf * 4]);
        acc0.x = fmaf(xv0.x, c0, acc0.x); acc0.y = fmaf(xv0.y, c0, acc0.y);
        acc0.z = fmaf(xv0.z, c0, acc0.z); acc0.w = fmaf(xv0.w, c0, acc0.w);
    }
    float in_n = inorm[node];
    float4 r;
    r.x = (acc0.x + acc1.x) * in_n;
    r.y = (acc0.y + acc1.y) * in_n;
    r.z = (acc0.z + acc1.z) * in_n;
    r.w = (acc0.w + acc1.w) * in_n;
    *reinterpret_cast<float4*>(&out[(size_t)node * NFEAT + lf * 4]) = r;
}

// ---------------- projection: out = agg @ W + b (in-place) ----------------
// 8 waves * 8 rows/wave; lane owns 2 cols. NOT __restrict__ on agg/outp (alias in-place).
__global__ __launch_bounds__(512)
void mm_kernel(const float* agg, float* outp, const float* __restrict__ W,
               const float* __restrict__ b, int N) {
    __shared__ float Wl[NFEAT * NFEAT];      // 64 KiB

    for (int i = threadIdx.x; i < (NFEAT * NFEAT) / 4; i += 512) {
        reinterpret_cast<float4*>(Wl)[i] = reinterpret_cast<const float4*>(W)[i];
    }
    __syncthreads();

    const int wave = threadIdx.x >> 6;
    const int lane = threadIdx.x & 63;
    const int c0 = 2 * lane;
    const int r0 = (blockIdx.x * 8 + wave) * 8;
    if (r0 >= N) return;

    const float b0 = b[c0];
    const float b1 = b[c0 + 1];

    float acc[8][2];
    #pragma unroll
    for (int r = 0; r < 8; ++r) { acc[r][0] = b0; acc[r][1] = b1; }

    const float* arow = agg + (size_t)r0 * NFEAT;

    for (int k4 = 0; k4 < NFEAT; k4 += 4) {
        float4 a[8];
        #pragma unroll
        for (int r = 0; r < 8; ++r) {
            a[r] = *reinterpret_cast<const float4*>(arow + r * NFEAT + k4);
        }
        #pragma unroll
        for (int kk = 0; kk < 4; ++kk) {
            float2 w = *reinterpret_cast<const float2*>(&Wl[(k4 + kk) * NFEAT + c0]);
            #pragma unroll
            for (int r = 0; r < 8; ++r) {
                float av = (kk == 0) ? a[r].x : (kk == 1) ? a[r].y : (kk == 2) ? a[r].z : a[r].w;
                acc[r][0] = fmaf(av, w.x, acc[r][0]);
                acc[r][1] = fmaf(av, w.y, acc[r][1]);
            }
        }
    }

    #pragma unroll
    for (int r = 0; r < 8; ++r) {
        *reinterpret_cast<float2*>(&outp[(size_t)(r0 + r) * NFEAT + c0]) =
            make_float2(acc[r][0], acc[r][1]);
    }
}

extern "C" void kernel_launch(void* const* d_in, const int* in_sizes, int n_in,
                              void* d_out, int out_size, void* d_ws, size_t ws_size,
                              hipStream_t stream) {
    const float* x   = (const float*)d_in[0];
    const int*   src = (const int*)d_in[1];
    const int*   dst = (const int*)d_in[2];
    const float* W   = (const float*)d_in[3];
    const float* b   = (const float*)d_in[4];

    const int N = in_sizes[0] / NFEAT;   // 100000
    const int E = in_sizes[1];           // 1600000
    float* out = (float*)d_out;

    const int NB = (N + BNODES - 1) >> BSHIFT;   // 196

    // ws layout (ints unless noted):
    // [out_deg N][bucket_cnt NB]   <- zeroed together
    // [bucket_base NB+1][bucket_cursor NB][row_start N+1][inorm N f32][csr_src E]
    int*   out_deg       = (int*)d_ws;
    int*   bucket_cnt    = out_deg + N;
    int*   bucket_base   = bucket_cnt + NB;
    int*   bucket_cursor = bucket_base + (NB + 1);
    int*   row_start     = bucket_cursor + NB;
    float* inorm         = (float*)(row_start + (N + 1));
    int*   csr_src       = (int*)(inorm + N);

    // packed edge array lives in d_out (E ints = 6.4MB << 51.2MB); dead before agg overwrites.
    int* packed = (int*)d_out;

    hipMemsetAsync(d_ws, 0, (size_t)(N + NB) * sizeof(int), stream);

    deg_kernel<<<(E + 255) / 256, 256, 0, stream>>>(src, E, out_deg);

    int nchunk = (E + CHUNK - 1) / CHUNK;        // 391
    bucket_count_kernel<<<nchunk, 256, 0, stream>>>(dst, E, bucket_cnt, NB);
    bucket_scan_kernel<<<1, 256, 0, stream>>>(bucket_cnt, bucket_base, bucket_cursor, NB);
    partition_kernel<<<nchunk, 256, 0, stream>>>(src, dst, E, bucket_cursor, packed, NB);
    binfill_kernel<<<NB, 512, 0, stream>>>(packed, bucket_base, row_start, inorm, csr_src, N, E);

    agg_kernel<<<(N + 7) / 8, 256, 0, stream>>>(x, csr_src, row_start, out_deg, inorm, out, N);

    mm_kernel<<<(N + 63) / 64, 512, 0, stream>>>(out, out, W, b, N);
}

// Round 5
// 252.885 us; speedup vs baseline: 11.7451x; 1.4164x over previous
//
#include <hip/hip_runtime.h>

#define NFEAT 128
#define BSHIFT 9
#define BNODES 512            // 1 << BSHIFT
#define NBMAX 256             // max buckets (N <= 131072)
#define CHUNK 4096            // edges per partition block

typedef __attribute__((ext_vector_type(8))) short bf16x8;
typedef __attribute__((ext_vector_type(4))) float f32x4;

__device__ inline unsigned short f2bf(float f) {            // RNE
    unsigned u = __float_as_uint(f);
    u += 0x7FFF + ((u >> 16) & 1);
    return (unsigned short)(u >> 16);
}
__device__ inline float bf2f(unsigned short h) {
    return __uint_as_float((unsigned)h << 16);
}

// ---------------- out-degree histogram (src) ----------------
__global__ void deg_kernel(const int* __restrict__ src, int E, int* __restrict__ out_deg) {
    int i = blockIdx.x * blockDim.x + threadIdx.x;
    if (i < E) atomicAdd(&out_deg[src[i]], 1);
}

// ---------------- pass A0: per-bucket edge counts ----------------
__global__ __launch_bounds__(256)
void bucket_count_kernel(const int* __restrict__ dst, int E,
                         int* __restrict__ bucket_cnt, int NB) {
    __shared__ int cnt[NBMAX];
    for (int i = threadIdx.x; i < NB; i += 256) cnt[i] = 0;
    __syncthreads();
    int base = blockIdx.x * CHUNK;
    int end = min(base + CHUNK, E);
    for (int j = base + threadIdx.x; j < end; j += 256)
        atomicAdd(&cnt[dst[j] >> BSHIFT], 1);
    __syncthreads();
    for (int i = threadIdx.x; i < NB; i += 256)
        if (cnt[i]) atomicAdd(&bucket_cnt[i], cnt[i]);
}

// ---------------- pass A1: scan bucket counts -> base & cursor ----------------
__global__ void bucket_scan_kernel(const int* __restrict__ bucket_cnt,
                                   int* __restrict__ bucket_base,
                                   int* __restrict__ bucket_cursor, int NB) {
    __shared__ int sa[256], sb[256];
    int tid = threadIdx.x;
    int v = (tid < NB) ? bucket_cnt[tid] : 0;
    sa[tid] = v;
    __syncthreads();
    int* s = sa; int* t = sb;
    for (int d = 1; d < 256; d <<= 1) {
        t[tid] = s[tid] + (tid >= d ? s[tid - d] : 0);
        __syncthreads();
        int* tmp = s; s = t; t = tmp;
    }
    int incl = s[tid];
    int excl = incl - v;
    if (tid < NB) { bucket_base[tid] = excl; bucket_cursor[tid] = excl; }
    if (tid == 255) bucket_base[NB] = incl;   // = E
}

// ---------------- pass A2: partition edges into bucket-ordered packed array ----------------
// packed = ((dst & 511) << 17) | src   (src < 2^17)
__global__ __launch_bounds__(256)
void partition_kernel(const int* __restrict__ src, const int* __restrict__ dst, int E,
                      int* __restrict__ bucket_cursor, int* __restrict__ packed, int NB) {
    __shared__ int cnt[NBMAX];
    for (int i = threadIdx.x; i < NB; i += 256) cnt[i] = 0;
    __syncthreads();
    int base = blockIdx.x * CHUNK;
    int end = min(base + CHUNK, E);
    for (int j = base + threadIdx.x; j < end; j += 256)
        atomicAdd(&cnt[dst[j] >> BSHIFT], 1);
    __syncthreads();
    for (int i = threadIdx.x; i < NB; i += 256) {
        int c = cnt[i];
        cnt[i] = c ? atomicAdd(&bucket_cursor[i], c) : 0;
    }
    __syncthreads();
    for (int j = base + threadIdx.x; j < end; j += 256) {
        int d = dst[j];
        int b = d >> BSHIFT;
        int pos = atomicAdd(&cnt[b], 1);
        packed[pos] = ((d & (BNODES - 1)) << 17) | src[j];
    }
}

// ---------------- pass B: per-bucket CSR fill (one block per bucket) ----------------
__global__ __launch_bounds__(512)
void binfill_kernel(const int* __restrict__ packed, const int* __restrict__ bucket_base,
                    int* __restrict__ row_start, float* __restrict__ inorm,
                    int* __restrict__ csr_src, int N, int E) {
    __shared__ int cnt[BNODES];
    __shared__ int sa[BNODES], sb[BNODES];
    int bkt = blockIdx.x;
    int node0 = bkt << BSHIFT;
    int nn = min(BNODES, N - node0);
    int beg = bucket_base[bkt];
    int end = bucket_base[bkt + 1];
    int tid = threadIdx.x;

    cnt[tid] = 0;
    __syncthreads();
    for (int i = beg + tid; i < end; i += 512)
        atomicAdd(&cnt[packed[i] >> 17], 1);
    __syncthreads();

    int v = cnt[tid];
    sa[tid] = v;
    __syncthreads();
    int* s = sa; int* t = sb;
    for (int d = 1; d < 512; d <<= 1) {
        t[tid] = s[tid] + (tid >= d ? s[tid - d] : 0);
        __syncthreads();
        int* tmp = s; s = t; t = tmp;
    }
    int excl = s[tid] - v;

    if (tid < nn) {
        row_start[node0 + tid] = beg + excl;
        inorm[node0 + tid] = rsqrtf((float)max(v, 1));
    }
    if (bkt == 0 && tid == 0) row_start[N] = E;
    __syncthreads();

    cnt[tid] = beg + excl;          // reuse as global cursor
    __syncthreads();
    for (int i = beg + tid; i < end; i += 512) {
        int p = packed[i];
        int slot = atomicAdd(&cnt[p >> 17], 1);
        csr_src[slot] = p & 0x1FFFF;
    }
}

// ================= BIG-WS (bf16/MFMA) PATH =================

// xh[i] = bf16(x[i] * rsqrt(max(out_deg,1)))  — one thread per 4 elements
__global__ __launch_bounds__(256)
void cast_kernel(const float* __restrict__ x, const int* __restrict__ out_deg,
                 unsigned short* __restrict__ xh, int N) {
    int t = blockIdx.x * 256 + threadIdx.x;
    int total = N * (NFEAT / 4);
    if (t >= total) return;
    int row = t >> 5;                       // 32 chunks per row
    float sc = rsqrtf((float)max(out_deg[row], 1));
    float4 v = reinterpret_cast<const float4*>(x)[t];
    ushort4 o;
    o.x = f2bf(v.x * sc); o.y = f2bf(v.y * sc);
    o.z = f2bf(v.z * sc); o.w = f2bf(v.w * sc);
    reinterpret_cast<ushort4*>(xh)[t] = o;
}

// Wt[col*128+k] = bf16(W[k*128+col])
__global__ void wt_kernel(const float* __restrict__ W, unsigned short* __restrict__ Wt) {
    int i = blockIdx.x * 256 + threadIdx.x;
    if (i < NFEAT * NFEAT) {
        int col = i >> 7, k = i & 127;
        Wt[i] = f2bf(W[k * NFEAT + col]);
    }
}

// gather bf16 rows, write agg row (bf16, inorm-scaled) STRIDED at d_out + node*512B
__global__ __launch_bounds__(256)
void agg_bf16_kernel(const unsigned short* __restrict__ xh, const int* __restrict__ csr_src,
                     const int* __restrict__ row_start, const float* __restrict__ inorm,
                     unsigned short* __restrict__ aggh, int N) {
    int node = blockIdx.x * 8 + (threadIdx.x >> 5);
    if (node >= N) return;
    int lf = threadIdx.x & 31;
    int beg = row_start[node];
    int end = row_start[node + 1];

    float4 a0 = make_float4(0.f, 0.f, 0.f, 0.f);
    float4 a1 = make_float4(0.f, 0.f, 0.f, 0.f);
    const ushort4* xr = reinterpret_cast<const ushort4*>(xh);
    int i = beg;
    for (; i + 1 < end; i += 2) {
        int s0 = csr_src[i];
        int s1 = csr_src[i + 1];
        ushort4 v0 = xr[s0 * 32 + lf];
        ushort4 v1 = xr[s1 * 32 + lf];
        a0.x += bf2f(v0.x); a0.y += bf2f(v0.y); a0.z += bf2f(v0.z); a0.w += bf2f(v0.w);
        a1.x += bf2f(v1.x); a1.y += bf2f(v1.y); a1.z += bf2f(v1.z); a1.w += bf2f(v1.w);
    }
    if (i < end) {
        int s0 = csr_src[i];
        ushort4 v0 = xr[s0 * 32 + lf];
        a0.x += bf2f(v0.x); a0.y += bf2f(v0.y); a0.z += bf2f(v0.z); a0.w += bf2f(v0.w);
    }
    float in_n = inorm[node];
    ushort4 o;
    o.x = f2bf((a0.x + a1.x) * in_n);
    o.y = f2bf((a0.y + a1.y) * in_n);
    o.z = f2bf((a0.z + a1.z) * in_n);
    o.w = f2bf((a0.w + a1.w) * in_n);
    // row slot = 512B (256 ushorts); payload = first 256B
    *reinterpret_cast<ushort4*>(aggh + (size_t)node * 256 + lf * 4) = o;
}

// MFMA projection: out[r][c] = sum_k aggh[r][k]*W[k][c] + b[c], in-place over d_out.
// Block = 128 rows, 256 thr = 4 waves (2x2), each wave 64x64. A+Wt staged in LDS, XOR-swizzled.
__global__ __launch_bounds__(256)
void mm_mfma_kernel(const unsigned short* __restrict__ aggh, float* outp,
                    const unsigned short* __restrict__ Wt, const float* __restrict__ b, int N) {
    __shared__ unsigned short Al[NFEAT * NFEAT];   // 32 KiB
    __shared__ unsigned short Bl[NFEAT * NFEAT];   // 32 KiB  (Wt: [col][k])
    int tid = threadIdx.x;
    int r0 = blockIdx.x * 128;

    // stage Wt (linear global -> swizzled LDS); 2048 x 16B chunks
    for (int c = tid; c < 2048; c += 256) {
        int col = c >> 4, sub = c & 15;
        int slot = sub ^ (col & 7);
        *reinterpret_cast<uint4*>(reinterpret_cast<char*>(Bl) + col * 256 + slot * 16) =
            *reinterpret_cast<const uint4*>(reinterpret_cast<const char*>(Wt) + c * 16);
    }
    // stage A rows r0..r0+127 from strided aggh (row slot 512B, payload 256B)
    for (int c = tid; c < 2048; c += 256) {
        int row = c >> 4, sub = c & 15;
        int grow = min(r0 + row, N - 1);
        int slot = sub ^ (row & 7);
        *reinterpret_cast<uint4*>(reinterpret_cast<char*>(Al) + row * 256 + slot * 16) =
            *reinterpret_cast<const uint4*>(reinterpret_cast<const char*>(aggh) +
                                            (size_t)grow * 512 + sub * 16);
    }
    __syncthreads();

    int lane = tid & 63;
    int wave = tid >> 6;
    int wr = wave >> 1, wc = wave & 1;
    int lrow = lane & 15, hi = lane >> 4;

    f32x4 zero = {0.f, 0.f, 0.f, 0.f};
    f32x4 acc[4][4];
    #pragma unroll
    for (int rt = 0; rt < 4; ++rt)
        #pragma unroll
        for (int ct = 0; ct < 4; ++ct) acc[rt][ct] = zero;

    #pragma unroll
    for (int ks = 0; ks < 4; ++ks) {
        int chunk = ks * 4 + hi;
        bf16x8 af[4], bfr[4];
        #pragma unroll
        for (int rt = 0; rt < 4; ++rt) {
            int row = wr * 64 + rt * 16 + lrow;
            af[rt] = *reinterpret_cast<bf16x8*>(reinterpret_cast<char*>(Al) + row * 256 +
                                                ((chunk ^ (row & 7)) * 16));
        }
        #pragma unroll
        for (int ct = 0; ct < 4; ++ct) {
            int col = wc * 64 + ct * 16 + lrow;
            bfr[ct] = *reinterpret_cast<bf16x8*>(reinterpret_cast<char*>(Bl) + col * 256 +
                                                 ((chunk ^ (col & 7)) * 16));
        }
        #pragma unroll
        for (int rt = 0; rt < 4; ++rt)
            #pragma unroll
            for (int ct = 0; ct < 4; ++ct)
                acc[rt][ct] = __builtin_amdgcn_mfma_f32_16x16x32_bf16(af[rt], bfr[ct],
                                                                     acc[rt][ct], 0, 0, 0);
    }

    // epilogue: D row = (lane>>4)*4 + q, col = lane&15 within each 16x16 tile
    #pragma unroll
    for (int ct = 0; ct < 4; ++ct) {
        int col = wc * 64 + ct * 16 + lrow;
        float bias = b[col];
        #pragma unroll
        for (int rt = 0; rt < 4; ++rt) {
            int rbase = r0 + wr * 64 + rt * 16 + hi * 4;
            #pragma unroll
            for (int q = 0; q < 4; ++q) {
                int row = rbase + q;
                if (row < N) outp[(size_t)row * NFEAT + col] = acc[rt][ct][q] + bias;
            }
        }
    }
}

// ================= SMALL-WS FALLBACK (round-4 proven f32 path) =================

__global__ __launch_bounds__(256)
void agg_kernel(const float* __restrict__ x, const int* __restrict__ csr_src,
                const int* __restrict__ row_start, const int* __restrict__ out_deg,
                const float* __restrict__ inorm, float* __restrict__ out, int N) {
    int node = blockIdx.x * 8 + (threadIdx.x >> 5);
    if (node >= N) return;
    int lf = threadIdx.x & 31;
    int beg = row_start[node];
    int end = row_start[node + 1];

    float4 acc0 = make_float4(0.f, 0.f, 0.f, 0.f);
    float4 acc1 = make_float4(0.f, 0.f, 0.f, 0.f);
    int i = beg;
    for (; i + 1 < end; i += 2) {
        int s0 = csr_src[i];
        int s1 = csr_src[i + 1];
        float c0 = rsqrtf((float)max(out_deg[s0], 1));
        float c1 = rsqrtf((float)max(out_deg[s1], 1));
        float4 xv0 = *reinterpret_cast<const float4*>(&x[(size_t)s0 * NFEAT + lf * 4]);
        float4 xv1 = *reinterpret_cast<const float4*>(&x[(size_t)s1 * NFEAT + lf * 4]);
        acc0.x = fmaf(xv0.x, c0, acc0.x); acc0.y = fmaf(xv0.y, c0, acc0.y);
        acc0.z = fmaf(xv0.z, c0, acc0.z); acc0.w = fmaf(xv0.w, c0, acc0.w);
        acc1.x = fmaf(xv1.x, c1, acc1.x); acc1.y = fmaf(xv1.y, c1, acc1.y);
        acc1.z = fmaf(xv1.z, c1, acc1.z); acc1.w = fmaf(xv1.w, c1, acc1.w);
    }
    if (i < end) {
        int s0 = csr_src[i];
        float c0 = rsqrtf((float)max(out_deg[s0], 1));
        float4 xv0 = *reinterpret_cast<const float4*>(&x[(size_t)s0 * NFEAT + lf * 4]);
        acc0.x = fmaf(xv0.x, c0, acc0.x); acc0.y = fmaf(xv0.y, c0, acc0.y);
        acc0.z = fmaf(xv0.z, c0, acc0.z); acc0.w = fmaf(xv0.w, c0, acc0.w);
    }
    float in_n = inorm[node];
    float4 r;
    r.x = (acc0.x + acc1.x) * in_n;
    r.y = (acc0.y + acc1.y) * in_n;
    r.z = (acc0.z + acc1.z) * in_n;
    r.w = (acc0.w + acc1.w) * in_n;
    *reinterpret_cast<float4*>(&out[(size_t)node * NFEAT + lf * 4]) = r;
}

__global__ __launch_bounds__(512)
void mm_kernel(const float* agg, float* outp, const float* __restrict__ W,
               const float* __restrict__ b, int N) {
    __shared__ float Wl[NFEAT * NFEAT];

    for (int i = threadIdx.x; i < (NFEAT * NFEAT) / 4; i += 512) {
        reinterpret_cast<float4*>(Wl)[i] = reinterpret_cast<const float4*>(W)[i];
    }
    __syncthreads();

    const int wave = threadIdx.x >> 6;
    const int lane = threadIdx.x & 63;
    const int c0 = 2 * lane;
    const int r0 = (blockIdx.x * 8 + wave) * 8;
    if (r0 >= N) return;

    const float b0 = b[c0];
    const float b1 = b[c0 + 1];

    float acc[8][2];
    #pragma unroll
    for (int r = 0; r < 8; ++r) { acc[r][0] = b0; acc[r][1] = b1; }

    const float* arow = agg + (size_t)r0 * NFEAT;

    for (int k4 = 0; k4 < NFEAT; k4 += 4) {
        float4 a[8];
        #pragma unroll
        for (int r = 0; r < 8; ++r) {
            a[r] = *reinterpret_cast<const float4*>(arow + r * NFEAT + k4);
        }
        #pragma unroll
        for (int kk = 0; kk < 4; ++kk) {
            float2 w = *reinterpret_cast<const float2*>(&Wl[(k4 + kk) * NFEAT + c0]);
            #pragma unroll
            for (int r = 0; r < 8; ++r) {
                float av = (kk == 0) ? a[r].x : (kk == 1) ? a[r].y : (kk == 2) ? a[r].z : a[r].w;
                acc[r][0] = fmaf(av, w.x, acc[r][0]);
                acc[r][1] = fmaf(av, w.y, acc[r][1]);
            }
        }
    }

    #pragma unroll
    for (int r = 0; r < 8; ++r) {
        *reinterpret_cast<float2*>(&outp[(size_t)(r0 + r) * NFEAT + c0]) =
            make_float2(acc[r][0], acc[r][1]);
    }
}

extern "C" void kernel_launch(void* const* d_in, const int* in_sizes, int n_in,
                              void* d_out, int out_size, void* d_ws, size_t ws_size,
                              hipStream_t stream) {
    const float* x   = (const float*)d_in[0];
    const int*   src = (const int*)d_in[1];
    const int*   dst = (const int*)d_in[2];
    const float* W   = (const float*)d_in[3];
    const float* b   = (const float*)d_in[4];

    const int N = in_sizes[0] / NFEAT;   // 100000
    const int E = in_sizes[1];           // 1600000
    float* out = (float*)d_out;

    const int NB = (N + BNODES - 1) >> BSHIFT;   // 196

    // common ws head: [out_deg N][bucket_cnt NB][bucket_base NB+1][bucket_cursor NB]
    //                 [row_start N+1][inorm N f32][csr_src E]
    int*   out_deg       = (int*)d_ws;
    int*   bucket_cnt    = out_deg + N;
    int*   bucket_base   = bucket_cnt + NB;
    int*   bucket_cursor = bucket_base + (NB + 1);
    int*   row_start     = bucket_cursor + NB;
    float* inorm         = (float*)(row_start + (N + 1));
    int*   csr_src       = (int*)(inorm + N);
    // big-path extras: [Wt 16384 bf16][xh N*128 bf16]
    unsigned short* Wt = (unsigned short*)(csr_src + E);
    unsigned short* xh = Wt + NFEAT * NFEAT;

    size_t need = (size_t)(csr_src + E - (int*)d_ws) * 4 +
                  (size_t)NFEAT * NFEAT * 2 + (size_t)N * NFEAT * 2;
    bool big = (ws_size >= need);

    // packed edge array lives in d_out[0, E*4) — dead before agg writes
    int* packed = (int*)d_out;

    hipMemsetAsync(d_ws, 0, (size_t)(N + NB) * sizeof(int), stream);

    deg_kernel<<<(E + 255) / 256, 256, 0, stream>>>(src, E, out_deg);

    int nchunk = (E + CHUNK - 1) / CHUNK;
    bucket_count_kernel<<<nchunk, 256, 0, stream>>>(dst, E, bucket_cnt, NB);
    bucket_scan_kernel<<<1, 256, 0, stream>>>(bucket_cnt, bucket_base, bucket_cursor, NB);
    partition_kernel<<<nchunk, 256, 0, stream>>>(src, dst, E, bucket_cursor, packed, NB);
    binfill_kernel<<<NB, 512, 0, stream>>>(packed, bucket_base, row_start, inorm, csr_src, N, E);

    if (big) {
        cast_kernel<<<(N * 32 + 255) / 256, 256, 0, stream>>>(x, out_deg, xh, N);
        wt_kernel<<<(NFEAT * NFEAT + 255) / 256, 256, 0, stream>>>(W, Wt);
        unsigned short* aggh = (unsigned short*)d_out;    // strided: row i at byte i*512
        agg_bf16_kernel<<<(N + 7) / 8, 256, 0, stream>>>(xh, csr_src, row_start, inorm, aggh, N);
        mm_mfma_kernel<<<(N + 127) / 128, 256, 0, stream>>>(aggh, out, Wt, b, N);
    } else {
        agg_kernel<<<(N + 7) / 8, 256, 0, stream>>>(x, csr_src, row_start, out_deg, inorm, out, N);
        mm_kernel<<<(N + 63) / 64, 512, 0, stream>>>(out, out, W, b, N);
    }
}

// Round 6
// 242.331 us; speedup vs baseline: 12.2566x; 1.0436x over previous
//
#include <hip/hip_runtime.h>

#define NFEAT 128
#define BSHIFT 9
#define BNODES 512            // 1 << BSHIFT
#define NBMAX 256             // max buckets (N <= 131072)
#define CHUNK 4096            // edges per partition block

typedef __attribute__((ext_vector_type(8))) short bf16x8;
typedef __attribute__((ext_vector_type(4))) float f32x4;

__device__ inline unsigned short f2bf(float f) {            // RNE
    unsigned u = __float_as_uint(f);
    u += 0x7FFF + ((u >> 16) & 1);
    return (unsigned short)(u >> 16);
}
__device__ inline float bf2f(unsigned short h) {
    return __uint_as_float((unsigned)h << 16);
}

// ---------------- fused: out-degree histogram + per-bucket edge counts ----------------
__global__ __launch_bounds__(256)
void edge_count_kernel(const int* __restrict__ src, const int* __restrict__ dst, int E,
                       int* __restrict__ out_deg, int* __restrict__ bucket_cnt, int NB) {
    __shared__ int cnt[NBMAX];
    for (int i = threadIdx.x; i < NB; i += 256) cnt[i] = 0;
    __syncthreads();
    int base = blockIdx.x * CHUNK;
    int end = min(base + CHUNK, E);
    for (int j = base + threadIdx.x; j < end; j += 256) {
        atomicAdd(&out_deg[src[j]], 1);
        atomicAdd(&cnt[dst[j] >> BSHIFT], 1);
    }
    __syncthreads();
    for (int i = threadIdx.x; i < NB; i += 256)
        if (cnt[i]) atomicAdd(&bucket_cnt[i], cnt[i]);
}

// ---------------- pass A1: scan bucket counts -> base & cursor ----------------
__global__ void bucket_scan_kernel(const int* __restrict__ bucket_cnt,
                                   int* __restrict__ bucket_base,
                                   int* __restrict__ bucket_cursor, int NB) {
    __shared__ int sa[256], sb[256];
    int tid = threadIdx.x;
    int v = (tid < NB) ? bucket_cnt[tid] : 0;
    sa[tid] = v;
    __syncthreads();
    int* s = sa; int* t = sb;
    for (int d = 1; d < 256; d <<= 1) {
        t[tid] = s[tid] + (tid >= d ? s[tid - d] : 0);
        __syncthreads();
        int* tmp = s; s = t; t = tmp;
    }
    int incl = s[tid];
    int excl = incl - v;
    if (tid < NB) { bucket_base[tid] = excl; bucket_cursor[tid] = excl; }
    if (tid == 255) bucket_base[NB] = incl;   // = E
}

// ---------------- pass A2: partition edges into bucket-ordered packed array ----------------
// packed = ((dst & 511) << 17) | src   (src < 2^17)
__global__ __launch_bounds__(256)
void partition_kernel(const int* __restrict__ src, const int* __restrict__ dst, int E,
                      int* __restrict__ bucket_cursor, int* __restrict__ packed, int NB) {
    __shared__ int cnt[NBMAX];
    for (int i = threadIdx.x; i < NB; i += 256) cnt[i] = 0;
    __syncthreads();
    int base = blockIdx.x * CHUNK;
    int end = min(base + CHUNK, E);
    for (int j = base + threadIdx.x; j < end; j += 256)
        atomicAdd(&cnt[dst[j] >> BSHIFT], 1);
    __syncthreads();
    for (int i = threadIdx.x; i < NB; i += 256) {
        int c = cnt[i];
        cnt[i] = c ? atomicAdd(&bucket_cursor[i], c) : 0;
    }
    __syncthreads();
    for (int j = base + threadIdx.x; j < end; j += 256) {
        int d = dst[j];
        int b = d >> BSHIFT;
        int pos = atomicAdd(&cnt[b], 1);
        packed[pos] = ((d & (BNODES - 1)) << 17) | src[j];
    }
}

// ---------------- pass B: per-bucket CSR fill (one block per bucket) ----------------
__global__ __launch_bounds__(512)
void binfill_kernel(const int* __restrict__ packed, const int* __restrict__ bucket_base,
                    int* __restrict__ row_start, float* __restrict__ inorm,
                    int* __restrict__ csr_src, int N, int E) {
    __shared__ int cnt[BNODES];
    __shared__ int sa[BNODES], sb[BNODES];
    int bkt = blockIdx.x;
    int node0 = bkt << BSHIFT;
    int nn = min(BNODES, N - node0);
    int beg = bucket_base[bkt];
    int end = bucket_base[bkt + 1];
    int tid = threadIdx.x;

    cnt[tid] = 0;
    __syncthreads();
    for (int i = beg + tid; i < end; i += 512)
        atomicAdd(&cnt[packed[i] >> 17], 1);
    __syncthreads();

    int v = cnt[tid];
    sa[tid] = v;
    __syncthreads();
    int* s = sa; int* t = sb;
    for (int d = 1; d < 512; d <<= 1) {
        t[tid] = s[tid] + (tid >= d ? s[tid - d] : 0);
        __syncthreads();
        int* tmp = s; s = t; t = tmp;
    }
    int excl = s[tid] - v;

    if (tid < nn) {
        row_start[node0 + tid] = beg + excl;
        inorm[node0 + tid] = rsqrtf((float)max(v, 1));
    }
    if (bkt == 0 && tid == 0) row_start[N] = E;
    __syncthreads();

    cnt[tid] = beg + excl;          // reuse as global cursor
    __syncthreads();
    for (int i = beg + tid; i < end; i += 512) {
        int p = packed[i];
        int slot = atomicAdd(&cnt[p >> 17], 1);
        csr_src[slot] = p & 0x1FFFF;
    }
}

// ================= BIG-WS (bf16/MFMA) PATH =================

// xh[i] = bf16(x[i] * rsqrt(max(out_deg,1)))  — one thread per 4 elements; tail threads do Wt.
__global__ __launch_bounds__(256)
void cast_kernel(const float* __restrict__ x, const int* __restrict__ out_deg,
                 unsigned short* __restrict__ xh,
                 const float* __restrict__ W, unsigned short* __restrict__ Wt, int N) {
    int t = blockIdx.x * 256 + threadIdx.x;
    int total = N * (NFEAT / 4);
    if (t < total) {
        int row = t >> 5;                       // 32 chunks per row
        float sc = rsqrtf((float)max(out_deg[row], 1));
        float4 v = reinterpret_cast<const float4*>(x)[t];
        ushort4 o;
        o.x = f2bf(v.x * sc); o.y = f2bf(v.y * sc);
        o.z = f2bf(v.z * sc); o.w = f2bf(v.w * sc);
        reinterpret_cast<ushort4*>(xh)[t] = o;
    } else {
        int i = t - total;
        if (i < NFEAT * NFEAT) {
            int col = i >> 7, k = i & 127;
            Wt[i] = f2bf(W[k * NFEAT + col]);   // Wt[col][k]
        }
    }
}

// gather bf16 rows; 8-wide batched index->gather pipeline (breaks dependent-load chain).
// Half-wave (32 lanes) per node; writes agg row (bf16, inorm-scaled) STRIDED at d_out + node*512B.
__global__ __launch_bounds__(256)
void agg_bf16_kernel(const unsigned short* __restrict__ xh, const int* __restrict__ csr_src,
                     const int* __restrict__ row_start, const float* __restrict__ inorm,
                     unsigned short* __restrict__ aggh, int N) {
    int node = blockIdx.x * 8 + (threadIdx.x >> 5);
    if (node >= N) return;
    int lf = threadIdx.x & 31;
    int beg = row_start[node];
    int end = row_start[node + 1];
    const ushort4* xr = reinterpret_cast<const ushort4*>(xh);

    float4 acc = make_float4(0.f, 0.f, 0.f, 0.f);
    for (int i = beg; i < end; i += 8) {
        int s[8];
        float m[8];
        #pragma unroll
        for (int u = 0; u < 8; ++u) {          // phase 1: 8 independent index loads
            int j = i + u;
            bool ok = (j < end);
            s[u] = ok ? csr_src[j] : 0;
            m[u] = ok ? 1.f : 0.f;
        }
        ushort4 v[8];
        #pragma unroll
        for (int u = 0; u < 8; ++u) {          // phase 2: 8 independent row gathers
            v[u] = xr[s[u] * 32 + lf];
        }
        #pragma unroll
        for (int u = 0; u < 8; ++u) {          // phase 3: masked accumulate
            acc.x = fmaf(m[u], bf2f(v[u].x), acc.x);
            acc.y = fmaf(m[u], bf2f(v[u].y), acc.y);
            acc.z = fmaf(m[u], bf2f(v[u].z), acc.z);
            acc.w = fmaf(m[u], bf2f(v[u].w), acc.w);
        }
    }
    float in_n = inorm[node];
    ushort4 o;
    o.x = f2bf(acc.x * in_n);
    o.y = f2bf(acc.y * in_n);
    o.z = f2bf(acc.z * in_n);
    o.w = f2bf(acc.w * in_n);
    *reinterpret_cast<ushort4*>(aggh + (size_t)node * 256 + lf * 4) = o;
}

// MFMA projection: out[r][c] = sum_k aggh[r][k]*W[k][c] + b[c], in-place over d_out.
__global__ __launch_bounds__(256)
void mm_mfma_kernel(const unsigned short* __restrict__ aggh, float* outp,
                    const unsigned short* __restrict__ Wt, const float* __restrict__ b, int N) {
    __shared__ unsigned short Al[NFEAT * NFEAT];   // 32 KiB
    __shared__ unsigned short Bl[NFEAT * NFEAT];   // 32 KiB  (Wt: [col][k])
    int tid = threadIdx.x;
    int r0 = blockIdx.x * 128;

    for (int c = tid; c < 2048; c += 256) {
        int col = c >> 4, sub = c & 15;
        int slot = sub ^ (col & 7);
        *reinterpret_cast<uint4*>(reinterpret_cast<char*>(Bl) + col * 256 + slot * 16) =
            *reinterpret_cast<const uint4*>(reinterpret_cast<const char*>(Wt) + c * 16);
    }
    for (int c = tid; c < 2048; c += 256) {
        int row = c >> 4, sub = c & 15;
        int grow = min(r0 + row, N - 1);
        int slot = sub ^ (row & 7);
        *reinterpret_cast<uint4*>(reinterpret_cast<char*>(Al) + row * 256 + slot * 16) =
            *reinterpret_cast<const uint4*>(reinterpret_cast<const char*>(aggh) +
                                            (size_t)grow * 512 + sub * 16);
    }
    __syncthreads();

    int lane = tid & 63;
    int wave = tid >> 6;
    int wr = wave >> 1, wc = wave & 1;
    int lrow = lane & 15, hi = lane >> 4;

    f32x4 zero = {0.f, 0.f, 0.f, 0.f};
    f32x4 acc[4][4];
    #pragma unroll
    for (int rt = 0; rt < 4; ++rt)
        #pragma unroll
        for (int ct = 0; ct < 4; ++ct) acc[rt][ct] = zero;

    #pragma unroll
    for (int ks = 0; ks < 4; ++ks) {
        int chunk = ks * 4 + hi;
        bf16x8 af[4], bfr[4];
        #pragma unroll
        for (int rt = 0; rt < 4; ++rt) {
            int row = wr * 64 + rt * 16 + lrow;
            af[rt] = *reinterpret_cast<bf16x8*>(reinterpret_cast<char*>(Al) + row * 256 +
                                                ((chunk ^ (row & 7)) * 16));
        }
        #pragma unroll
        for (int ct = 0; ct < 4; ++ct) {
            int col = wc * 64 + ct * 16 + lrow;
            bfr[ct] = *reinterpret_cast<bf16x8*>(reinterpret_cast<char*>(Bl) + col * 256 +
                                                 ((chunk ^ (col & 7)) * 16));
        }
        #pragma unroll
        for (int rt = 0; rt < 4; ++rt)
            #pragma unroll
            for (int ct = 0; ct < 4; ++ct)
                acc[rt][ct] = __builtin_amdgcn_mfma_f32_16x16x32_bf16(af[rt], bfr[ct],
                                                                     acc[rt][ct], 0, 0, 0);
    }

    #pragma unroll
    for (int ct = 0; ct < 4; ++ct) {
        int col = wc * 64 + ct * 16 + lrow;
        float bias = b[col];
        #pragma unroll
        for (int rt = 0; rt < 4; ++rt) {
            int rbase = r0 + wr * 64 + rt * 16 + hi * 4;
            #pragma unroll
            for (int q = 0; q < 4; ++q) {
                int row = rbase + q;
                if (row < N) outp[(size_t)row * NFEAT + col] = acc[rt][ct][q] + bias;
            }
        }
    }
}

// ================= SMALL-WS FALLBACK (proven f32 path) =================

__global__ __launch_bounds__(256)
void agg_kernel(const float* __restrict__ x, const int* __restrict__ csr_src,
                const int* __restrict__ row_start, const int* __restrict__ out_deg,
                const float* __restrict__ inorm, float* __restrict__ out, int N) {
    int node = blockIdx.x * 8 + (threadIdx.x >> 5);
    if (node >= N) return;
    int lf = threadIdx.x & 31;
    int beg = row_start[node];
    int end = row_start[node + 1];

    float4 acc0 = make_float4(0.f, 0.f, 0.f, 0.f);
    float4 acc1 = make_float4(0.f, 0.f, 0.f, 0.f);
    int i = beg;
    for (; i + 1 < end; i += 2) {
        int s0 = csr_src[i];
        int s1 = csr_src[i + 1];
        float c0 = rsqrtf((float)max(out_deg[s0], 1));
        float c1 = rsqrtf((float)max(out_deg[s1], 1));
        float4 xv0 = *reinterpret_cast<const float4*>(&x[(size_t)s0 * NFEAT + lf * 4]);
        float4 xv1 = *reinterpret_cast<const float4*>(&x[(size_t)s1 * NFEAT + lf * 4]);
        acc0.x = fmaf(xv0.x, c0, acc0.x); acc0.y = fmaf(xv0.y, c0, acc0.y);
        acc0.z = fmaf(xv0.z, c0, acc0.z); acc0.w = fmaf(xv0.w, c0, acc0.w);
        acc1.x = fmaf(xv1.x, c1, acc1.x); acc1.y = fmaf(xv1.y, c1, acc1.y);
        acc1.z = fmaf(xv1.z, c1, acc1.z); acc1.w = fmaf(xv1.w, c1, acc1.w);
    }
    if (i < end) {
        int s0 = csr_src[i];
        float c0 = rsqrtf((float)max(out_deg[s0], 1));
        float4 xv0 = *reinterpret_cast<const float4*>(&x[(size_t)s0 * NFEAT + lf * 4]);
        acc0.x = fmaf(xv0.x, c0, acc0.x); acc0.y = fmaf(xv0.y, c0, acc0.y);
        acc0.z = fmaf(xv0.z, c0, acc0.z); acc0.w = fmaf(xv0.w, c0, acc0.w);
    }
    float in_n = inorm[node];
    float4 r;
    r.x = (acc0.x + acc1.x) * in_n;
    r.y = (acc0.y + acc1.y) * in_n;
    r.z = (acc0.z + acc1.z) * in_n;
    r.w = (acc0.w + acc1.w) * in_n;
    *reinterpret_cast<float4*>(&out[(size_t)node * NFEAT + lf * 4]) = r;
}

__global__ __launch_bounds__(512)
void mm_kernel(const float* agg, float* outp, const float* __restrict__ W,
               const float* __restrict__ b, int N) {
    __shared__ float Wl[NFEAT * NFEAT];

    for (int i = threadIdx.x; i < (NFEAT * NFEAT) / 4; i += 512) {
        reinterpret_cast<float4*>(Wl)[i] = reinterpret_cast<const float4*>(W)[i];
    }
    __syncthreads();

    const int wave = threadIdx.x >> 6;
    const int lane = threadIdx.x & 63;
    const int c0 = 2 * lane;
    const int r0 = (blockIdx.x * 8 + wave) * 8;
    if (r0 >= N) return;

    const float b0 = b[c0];
    const float b1 = b[c0 + 1];

    float acc[8][2];
    #pragma unroll
    for (int r = 0; r < 8; ++r) { acc[r][0] = b0; acc[r][1] = b1; }

    const float* arow = agg + (size_t)r0 * NFEAT;

    for (int k4 = 0; k4 < NFEAT; k4 += 4) {
        float4 a[8];
        #pragma unroll
        for (int r = 0; r < 8; ++r) {
            a[r] = *reinterpret_cast<const float4*>(arow + r * NFEAT + k4);
        }
        #pragma unroll
        for (int kk = 0; kk < 4; ++kk) {
            float2 w = *reinterpret_cast<const float2*>(&Wl[(k4 + kk) * NFEAT + c0]);
            #pragma unroll
            for (int r = 0; r < 8; ++r) {
                float av = (kk == 0) ? a[r].x : (kk == 1) ? a[r].y : (kk == 2) ? a[r].z : a[r].w;
                acc[r][0] = fmaf(av, w.x, acc[r][0]);
                acc[r][1] = fmaf(av, w.y, acc[r][1]);
            }
        }
    }

    #pragma unroll
    for (int r = 0; r < 8; ++r) {
        *reinterpret_cast<float2*>(&outp[(size_t)(r0 + r) * NFEAT + c0]) =
            make_float2(acc[r][0], acc[r][1]);
    }
}

extern "C" void kernel_launch(void* const* d_in, const int* in_sizes, int n_in,
                              void* d_out, int out_size, void* d_ws, size_t ws_size,
                              hipStream_t stream) {
    const float* x   = (const float*)d_in[0];
    const int*   src = (const int*)d_in[1];
    const int*   dst = (const int*)d_in[2];
    const float* W   = (const float*)d_in[3];
    const float* b   = (const float*)d_in[4];

    const int N = in_sizes[0] / NFEAT;   // 100000
    const int E = in_sizes[1];           // 1600000
    float* out = (float*)d_out;

    const int NB = (N + BNODES - 1) >> BSHIFT;   // 196

    int*   out_deg       = (int*)d_ws;
    int*   bucket_cnt    = out_deg + N;
    int*   bucket_base   = bucket_cnt + NB;
    int*   bucket_cursor = bucket_base + (NB + 1);
    int*   row_start     = bucket_cursor + NB;
    float* inorm         = (float*)(row_start + (N + 1));
    int*   csr_src       = (int*)(inorm + N);
    unsigned short* Wt = (unsigned short*)(csr_src + E);
    unsigned short* xh = Wt + NFEAT * NFEAT;

    size_t need = (size_t)(csr_src + E - (int*)d_ws) * 4 +
                  (size_t)NFEAT * NFEAT * 2 + (size_t)N * NFEAT * 2;
    bool big = (ws_size >= need);

    // packed edge array lives in d_out[0, E*4) — dead before agg writes
    int* packed = (int*)d_out;

    hipMemsetAsync(d_ws, 0, (size_t)(N + NB) * sizeof(int), stream);

    int nchunk = (E + CHUNK - 1) / CHUNK;
    edge_count_kernel<<<nchunk, 256, 0, stream>>>(src, dst, E, out_deg, bucket_cnt, NB);
    bucket_scan_kernel<<<1, 256, 0, stream>>>(bucket_cnt, bucket_base, bucket_cursor, NB);
    partition_kernel<<<nchunk, 256, 0, stream>>>(src, dst, E, bucket_cursor, packed, NB);
    binfill_kernel<<<NB, 512, 0, stream>>>(packed, bucket_base, row_start, inorm, csr_src, N, E);

    if (big) {
        int cast_threads = N * 32 + NFEAT * NFEAT;
        cast_kernel<<<(cast_threads + 255) / 256, 256, 0, stream>>>(x, out_deg, xh, W, Wt, N);
        unsigned short* aggh = (unsigned short*)d_out;    // strided: row i at byte i*512
        agg_bf16_kernel<<<(N + 7) / 8, 256, 0, stream>>>(xh, csr_src, row_start, inorm, aggh, N);
        mm_mfma_kernel<<<(N + 127) / 128, 256, 0, stream>>>(aggh, out, Wt, b, N);
    } else {
        agg_kernel<<<(N + 7) / 8, 256, 0, stream>>>(x, csr_src, row_start, out_deg, inorm, out, N);
        mm_kernel<<<(N + 63) / 64, 512, 0, stream>>>(out, out, W, b, N);
    }
}